// Round 1
// baseline (19838.432 us; speedup 1.0000x reference)
//
#include <hip/hip_runtime.h>

#define T_STEPS 512
#define BATCH   256
#define DIM     1024
#define NOUT    5
#define BH      (BATCH*DIM)

typedef short s16x8 __attribute__((ext_vector_type(8)));
typedef float f32x4 __attribute__((ext_vector_type(4)));
typedef unsigned short u16;
typedef unsigned int   u32;

__device__ __forceinline__ u16 f2bf(float f) {
    union { float f; u32 u; } v; v.f = f;
    u32 r = v.u + 0x7FFFu + ((v.u >> 16) & 1u);   // RNE
    return (u16)(r >> 16);
}
__device__ __forceinline__ float bf2f(u16 u) {
    union { u32 u; float f; } v; v.u = ((u32)u) << 16;
    return v.f;
}
__device__ __forceinline__ s16x8 cvt8(float4 a, float4 b) {
    s16x8 v;
    v[0]=(short)f2bf(a.x); v[1]=(short)f2bf(a.y); v[2]=(short)f2bf(a.z); v[3]=(short)f2bf(a.w);
    v[4]=(short)f2bf(b.x); v[5]=(short)f2bf(b.y); v[6]=(short)f2bf(b.z); v[7]=(short)f2bf(b.w);
    return v;
}

// ---------------------------------------------------------------- convert fp32 -> bf16
__global__ __launch_bounds__(256) void cvt_kernel(const float* __restrict__ src,
                                                  u16* __restrict__ dst, int n4) {
    int i = blockIdx.x * 256 + threadIdx.x;
    if (i < n4) {
        float4 x = ((const float4*)src)[i];
        ushort4 o;
        o.x = f2bf(x.x); o.y = f2bf(x.y); o.z = f2bf(x.z); o.w = f2bf(x.w);
        ((ushort4*)dst)[i] = o;
    }
}

// ---------------------------------------------------------------- Phase 1: E = X @ W_in^T + b_in
// C[131072 x 1024] tiles 128x128, BK=64. A (X, fp32) staged manually with inline cvt
// into padded LDS; B (W_in bf16) staged via global_load_lds w=16 with XOR swizzle.
#define PADA 88   // shorts per LDS row of A: 176B stride -> conflict-free b128, 16B aligned

__global__ __launch_bounds__(256, 2) void gemm_e(
    const float* __restrict__ X,    // [131072][1024] fp32
    const u16*   __restrict__ Wb,   // [1024][1024] bf16 (row = out col, K contiguous)
    const float* __restrict__ b_in, // [1024]
    u16*         __restrict__ E)    // [131072][1024] bf16
{
    __shared__ u16 sA[128 * PADA];
    __shared__ u16 sB[128 * 64];

    const int K = 1024;
    int tid  = threadIdx.x;
    int lane = tid & 63, wv = tid >> 6;
    int lm   = lane & 15, quad = lane >> 4;
    int bm   = blockIdx.x >> 3, bn = blockIdx.x & 7;
    int wm   = wv >> 1, wn = wv & 1;

    float bias[4];
#pragma unroll
    for (int nt = 0; nt < 4; ++nt)
        bias[nt] = b_in[bn*128 + wn*64 + nt*16 + lm];

    f32x4 acc[4][4];
#pragma unroll
    for (int a = 0; a < 4; ++a)
#pragma unroll
        for (int b = 0; b < 4; ++b)
            acc[a][b] = (f32x4){0.f, 0.f, 0.f, 0.f};

    // B staging lane geometry (swizzled on the GLOBAL side; LDS is lane-contiguous)
    int colB  = (lane & 7) ^ (lane >> 3);   // global col8 this lane fetches
    int rowB0 = lane >> 3;                  // row within 8-row chunk

    for (int kk = 0; kk < K; kk += 64) {
        // async-stage B: 16 chunks of 1KB; wave wv does chunks i*4+wv
#pragma unroll
        for (int i = 0; i < 4; ++i) {
            int q   = i*4 + wv;
            int row = q*8 + rowB0;
            const u16* gp = Wb + (size_t)(bn*128 + row)*K + kk + colB*8;
            __builtin_amdgcn_global_load_lds(
                (const __attribute__((address_space(1))) void*)gp,
                (__attribute__((address_space(3))) void*)(sB + q*512),
                16, 0, 0);
        }
        // stage A with fp32->bf16 convert
#pragma unroll
        for (int p = 0; p < 4; ++p) {
            int row = (tid >> 3) + 32*p;
            int k8  = (tid & 7) * 8;
            const float* gp = X + (size_t)(bm*128 + row)*K + kk + k8;
            float4 x0 = ((const float4*)gp)[0];
            float4 x1 = ((const float4*)gp)[1];
            *(s16x8*)&sA[row*PADA + k8] = cvt8(x0, x1);
        }
        __syncthreads();
#pragma unroll
        for (int kc = 0; kc < 2; ++kc) {
            s16x8 af[4], bfr[4];
#pragma unroll
            for (int mt = 0; mt < 4; ++mt) {
                int row = wm*64 + mt*16 + lm;
                af[mt] = *(const s16x8*)&sA[row*PADA + kc*32 + quad*8];
            }
            int c8 = kc*4 + quad;
#pragma unroll
            for (int nt = 0; nt < 4; ++nt) {
                int row = wn*64 + nt*16 + lm;
                bfr[nt] = *(const s16x8*)&sB[row*64 + ((c8 ^ (row & 7)) * 8)];
            }
#pragma unroll
            for (int mt = 0; mt < 4; ++mt)
#pragma unroll
                for (int nt = 0; nt < 4; ++nt)
                    acc[mt][nt] = __builtin_amdgcn_mfma_f32_16x16x32_bf16(
                        af[mt], bfr[nt], acc[mt][nt], 0, 0, 0);
        }
        __syncthreads();
    }
    // epilogue: + bias, cvt bf16, store
#pragma unroll
    for (int mt = 0; mt < 4; ++mt)
#pragma unroll
        for (int nt = 0; nt < 4; ++nt)
#pragma unroll
            for (int i = 0; i < 4; ++i) {
                int row = bm*128 + wm*64 + mt*16 + quad*4 + i;
                int col = bn*128 + wn*64 + nt*16 + lm;
                E[(size_t)row*1024 + col] = f2bf(acc[mt][nt][i] + bias[nt]);
            }
}

// ---------------------------------------------------------------- Phase 2: recurrence
// 256 WGs = 16 row-groups x 16 col-groups. WG: 4 waves, each holds W_h slice
// [16 cols x 256 K] as 32 bf16 B-fragments in 128 VGPRs (loaded once).
// K split across waves -> LDS reduction. Row-group sync via atomic counter.
__global__ __launch_bounds__(256, 1) void rnn_phase2(
    const float* __restrict__ h0,   // [256][1024] fp32
    const float* __restrict__ Wh,   // [1024][1024] fp32 (row = out col)
    const float* __restrict__ bh,   // [1024]
    const u16*   __restrict__ E,    // [512][256][1024] bf16
    u16*         __restrict__ hbuf, // [2][256][1024] bf16
    u32*         __restrict__ cnt,  // 16 counters spaced 32 u32 apart
    float*       __restrict__ hidden_out) // [256][1024] fp32
{
    __shared__ float red[4][16][68];
    int tid  = threadIdx.x;
    int lane = tid & 63, wv = tid >> 6;
    int lm   = lane & 15, quad = lane >> 4;
    int r    = blockIdx.x >> 4, c = blockIdx.x & 15;

    // --- persistent W_h fragments (one-time load, fp32 -> bf16)
    s16x8 wf[4][8];
#pragma unroll
    for (int ct = 0; ct < 4; ++ct)
#pragma unroll
        for (int kc = 0; kc < 8; ++kc) {
            int n = c*64 + ct*16 + lm;
            int k = wv*256 + kc*32 + quad*8;
            const float* p = Wh + (size_t)n*1024 + k;
            float4 x0 = ((const float4*)p)[0];
            float4 x1 = ((const float4*)p)[1];
            wf[ct][kc] = cvt8(x0, x1);
        }

    int m  = tid >> 4;          // reduce-phase row 0..15
    int n4 = (tid & 15) * 4;    // reduce-phase col base (of 64)
    float4 bh4 = *(const float4*)&bh[c*64 + n4];
    int rowA = r*16 + lm;
    u32* cptr = cnt + r*32;

    for (int t = 0; t < T_STEPS; ++t) {
        // E[t] is race-free (phase-1 data): start its load before the wait
        ushort4 e4 = *(const ushort4*)&E[(size_t)t*BH + (size_t)(r*16 + m)*1024 + c*64 + n4];

        if (t > 0) {
            if (tid == 0) {
                u32 target = (u32)(16*t);
                while (__hip_atomic_load(cptr, __ATOMIC_RELAXED, __HIP_MEMORY_SCOPE_AGENT) < target)
                    __builtin_amdgcn_s_sleep(1);
            }
            __syncthreads();
            __builtin_amdgcn_fence(__ATOMIC_ACQUIRE, "agent");  // per-wave L1/L2 inv
        }

        // A fragments: h rows for this group, this wave's K quarter
        s16x8 af[8];
        if (t == 0) {
#pragma unroll
            for (int kc = 0; kc < 8; ++kc) {
                const float* p = h0 + (size_t)rowA*1024 + wv*256 + kc*32 + quad*8;
                float4 x0 = ((const float4*)p)[0];
                float4 x1 = ((const float4*)p)[1];
                af[kc] = cvt8(x0, x1);
            }
        } else {
            const u16* hb = hbuf + (size_t)(t & 1)*BH;
#pragma unroll
            for (int kc = 0; kc < 8; ++kc)
                af[kc] = *(const s16x8*)&hb[(size_t)rowA*1024 + wv*256 + kc*32 + quad*8];
        }

        f32x4 acc[4];
#pragma unroll
        for (int ct = 0; ct < 4; ++ct) acc[ct] = (f32x4){0.f, 0.f, 0.f, 0.f};
#pragma unroll
        for (int kc = 0; kc < 8; ++kc)
#pragma unroll
            for (int ct = 0; ct < 4; ++ct)
                acc[ct] = __builtin_amdgcn_mfma_f32_16x16x32_bf16(af[kc], wf[ct][kc], acc[ct], 0, 0, 0);

        // K-partial results -> LDS  (D layout: row = quad*4+i, col = lm)
#pragma unroll
        for (int ct = 0; ct < 4; ++ct)
#pragma unroll
            for (int i = 0; i < 4; ++i)
                red[wv][quad*4 + i][ct*16 + lm] = acc[ct][i];
        __syncthreads();

        // reduce 4 wave-partials + bias + e, sigmoid, store
        float4 p0 = *(const float4*)&red[0][m][n4];
        float4 p1 = *(const float4*)&red[1][m][n4];
        float4 p2 = *(const float4*)&red[2][m][n4];
        float4 p3 = *(const float4*)&red[3][m][n4];
        float4 s;
        s.x = p0.x + p1.x + p2.x + p3.x + bh4.x + bf2f(e4.x);
        s.y = p0.y + p1.y + p2.y + p3.y + bh4.y + bf2f(e4.y);
        s.z = p0.z + p1.z + p2.z + p3.z + bh4.z + bf2f(e4.z);
        s.w = p0.w + p1.w + p2.w + p3.w + bh4.w + bf2f(e4.w);
        float4 h;
        h.x = 1.f / (1.f + __expf(-s.x));
        h.y = 1.f / (1.f + __expf(-s.y));
        h.z = 1.f / (1.f + __expf(-s.z));
        h.w = 1.f / (1.f + __expf(-s.w));

        ushort4 hb4;
        hb4.x = f2bf(h.x); hb4.y = f2bf(h.y); hb4.z = f2bf(h.z); hb4.w = f2bf(h.w);
        *(ushort4*)&hbuf[(size_t)((t + 1) & 1)*BH + (size_t)(r*16 + m)*1024 + c*64 + n4] = hb4;
        if (t == T_STEPS - 1)
            *(float4*)&hidden_out[(size_t)(r*16 + m)*1024 + c*64 + n4] = h;

        __threadfence();     // flush this wave's stores to the coherent point
        __syncthreads();     // all waves flushed + LDS reduce reads done
        if (tid == 0)
            __hip_atomic_fetch_add(cptr, 1u, __ATOMIC_RELAXED, __HIP_MEMORY_SCOPE_AGENT);
    }
}

// ---------------------------------------------------------------- Phase 3: log_softmax(h W_o^T + b_o)
__global__ __launch_bounds__(64) void head_kernel(const float* __restrict__ h,
                                                  const float* __restrict__ Wo,
                                                  const float* __restrict__ bo,
                                                  float* __restrict__ out)
{
    int b = blockIdx.x, l = threadIdx.x;
    float a0 = 0.f, a1 = 0.f, a2 = 0.f, a3 = 0.f, a4 = 0.f;
    for (int k = l; k < DIM; k += 64) {
        float hv = h[b*DIM + k];
        a0 += hv * Wo[0*DIM + k];
        a1 += hv * Wo[1*DIM + k];
        a2 += hv * Wo[2*DIM + k];
        a3 += hv * Wo[3*DIM + k];
        a4 += hv * Wo[4*DIM + k];
    }
#pragma unroll
    for (int off = 32; off >= 1; off >>= 1) {
        a0 += __shfl_down(a0, off);
        a1 += __shfl_down(a1, off);
        a2 += __shfl_down(a2, off);
        a3 += __shfl_down(a3, off);
        a4 += __shfl_down(a4, off);
    }
    if (l == 0) {
        float v[5] = {a0 + bo[0], a1 + bo[1], a2 + bo[2], a3 + bo[3], a4 + bo[4]};
        float mx = v[0];
#pragma unroll
        for (int o = 1; o < 5; ++o) mx = fmaxf(mx, v[o]);
        float sum = 0.f;
#pragma unroll
        for (int o = 0; o < 5; ++o) sum += __expf(v[o] - mx);
        float lse = mx + __logf(sum);
#pragma unroll
        for (int o = 0; o < 5; ++o) out[b*NOUT + o] = v[o] - lse;
    }
}

// ---------------------------------------------------------------- launch
extern "C" void kernel_launch(void* const* d_in, const int* in_sizes, int n_in,
                              void* d_out, int out_size, void* d_ws, size_t ws_size,
                              hipStream_t stream)
{
    const float* X   = (const float*)d_in[0];
    const float* h0  = (const float*)d_in[1];
    const float* st  = (const float*)d_in[2];
    const float* Win = (const float*)d_in[3];
    const float* bin = (const float*)d_in[4];
    const float* Wh  = (const float*)d_in[5];
    const float* bhp = (const float*)d_in[6];
    const float* Wo  = (const float*)d_in[7];
    const float* bo  = (const float*)d_in[8];

    char* ws   = (char*)d_ws;
    u32*  cnt  = (u32*)ws;                                        // 4 KB
    u16*  hbuf = (u16*)(ws + 4096);                               // 1 MB
    u16*  Wbf  = (u16*)(ws + 4096 + (size_t)2*BH*2);              // 2 MB
    u16*  E    = (u16*)(ws + 4096 + (size_t)2*BH*2 + (size_t)DIM*DIM*2); // 268 MB

    float* out_lp = (float*)d_out;          // [256][5]
    float* out_h  = out_lp + BATCH*NOUT;    // [256][1024]
    float* out_st = out_h + BH;             // [256][1024]

    hipMemsetAsync(cnt, 0, 4096, stream);
    cvt_kernel<<<(DIM*DIM/4 + 255)/256, 256, 0, stream>>>(Win, Wbf, DIM*DIM/4);
    gemm_e<<<(T_STEPS*BATCH/128)*8, 256, 0, stream>>>(X, Wbf, bin, E);
    rnn_phase2<<<256, 256, 0, stream>>>(h0, Wh, bhp, E, hbuf, cnt, out_h);
    head_kernel<<<BATCH, 64, 0, stream>>>(out_h, Wo, bo, out_lp);
    hipMemcpyAsync(out_st, st, (size_t)BH*sizeof(float), hipMemcpyDeviceToDevice, stream);
}

// Round 2
// 2755.416 us; speedup vs baseline: 7.1998x; 7.1998x over previous
//
#include <hip/hip_runtime.h>

#define T_STEPS 512
#define BATCH   256
#define DIM     1024
#define NOUT    5
#define BH      (BATCH*DIM)

typedef short s16x8 __attribute__((ext_vector_type(8)));
typedef float f32x4 __attribute__((ext_vector_type(4)));
typedef unsigned short u16;
typedef unsigned int   u32;

__device__ __forceinline__ u16 f2bf(float f) {
    union { float f; u32 u; } v; v.f = f;
    u32 r = v.u + 0x7FFFu + ((v.u >> 16) & 1u);   // RNE
    return (u16)(r >> 16);
}
__device__ __forceinline__ float bf2f(u16 u) {
    union { u32 u; float f; } v; v.u = ((u32)u) << 16;
    return v.f;
}
__device__ __forceinline__ s16x8 cvt8(float4 a, float4 b) {
    s16x8 v;
    v[0]=(short)f2bf(a.x); v[1]=(short)f2bf(a.y); v[2]=(short)f2bf(a.z); v[3]=(short)f2bf(a.w);
    v[4]=(short)f2bf(b.x); v[5]=(short)f2bf(b.y); v[6]=(short)f2bf(b.z); v[7]=(short)f2bf(b.w);
    return v;
}

// --- per-instruction coherent (LLC-level) memory ops: bypass L1+L2 (sc0 sc1).
// These make cross-XCD data visible WITHOUT bulk buffer_wbl2/buffer_inv fences.
__device__ __forceinline__ void ldg_cv16_issue(const u16* p, s16x8* dst) {
    asm volatile("global_load_dwordx4 %0, %1, off sc0 sc1"
                 : "=v"(*dst) : "v"(p) : "memory");
}
__device__ __forceinline__ void stg_cv8(u16* p, ushort4 v) {
    asm volatile("global_store_dwordx2 %0, %1, off sc0 sc1"
                 :: "v"(p), "v"(v) : "memory");
}
__device__ __forceinline__ void wait_vm0() {
    asm volatile("s_waitcnt vmcnt(0)" ::: "memory");
}

// ---------------------------------------------------------------- convert fp32 -> bf16
__global__ __launch_bounds__(256) void cvt_kernel(const float* __restrict__ src,
                                                  u16* __restrict__ dst, int n4) {
    int i = blockIdx.x * 256 + threadIdx.x;
    if (i < n4) {
        float4 x = ((const float4*)src)[i];
        ushort4 o;
        o.x = f2bf(x.x); o.y = f2bf(x.y); o.z = f2bf(x.z); o.w = f2bf(x.w);
        ((ushort4*)dst)[i] = o;
    }
}

// ---------------------------------------------------------------- Phase 1: E = X @ W_in^T + b_in
#define PADA 88   // shorts per LDS row of A: 176B stride -> conflict-free b128, 16B aligned

__global__ __launch_bounds__(256, 2) void gemm_e(
    const float* __restrict__ X,    // [131072][1024] fp32
    const u16*   __restrict__ Wb,   // [1024][1024] bf16 (row = out col, K contiguous)
    const float* __restrict__ b_in, // [1024]
    u16*         __restrict__ E)    // [131072][1024] bf16
{
    __shared__ u16 sA[128 * PADA];
    __shared__ u16 sB[128 * 64];

    const int K = 1024;
    int tid  = threadIdx.x;
    int lane = tid & 63, wv = tid >> 6;
    int lm   = lane & 15, quad = lane >> 4;
    int bm   = blockIdx.x >> 3, bn = blockIdx.x & 7;
    int wm   = wv >> 1, wn = wv & 1;

    float bias[4];
#pragma unroll
    for (int nt = 0; nt < 4; ++nt)
        bias[nt] = b_in[bn*128 + wn*64 + nt*16 + lm];

    f32x4 acc[4][4];
#pragma unroll
    for (int a = 0; a < 4; ++a)
#pragma unroll
        for (int b = 0; b < 4; ++b)
            acc[a][b] = (f32x4){0.f, 0.f, 0.f, 0.f};

    int colB  = (lane & 7) ^ (lane >> 3);
    int rowB0 = lane >> 3;

    for (int kk = 0; kk < K; kk += 64) {
#pragma unroll
        for (int i = 0; i < 4; ++i) {
            int q   = i*4 + wv;
            int row = q*8 + rowB0;
            const u16* gp = Wb + (size_t)(bn*128 + row)*K + kk + colB*8;
            __builtin_amdgcn_global_load_lds(
                (const __attribute__((address_space(1))) void*)gp,
                (__attribute__((address_space(3))) void*)(sB + q*512),
                16, 0, 0);
        }
#pragma unroll
        for (int p = 0; p < 4; ++p) {
            int row = (tid >> 3) + 32*p;
            int k8  = (tid & 7) * 8;
            const float* gp = X + (size_t)(bm*128 + row)*K + kk + k8;
            float4 x0 = ((const float4*)gp)[0];
            float4 x1 = ((const float4*)gp)[1];
            *(s16x8*)&sA[row*PADA + k8] = cvt8(x0, x1);
        }
        __syncthreads();
#pragma unroll
        for (int kc = 0; kc < 2; ++kc) {
            s16x8 af[4], bfr[4];
#pragma unroll
            for (int mt = 0; mt < 4; ++mt) {
                int row = wm*64 + mt*16 + lm;
                af[mt] = *(const s16x8*)&sA[row*PADA + kc*32 + quad*8];
            }
            int c8 = kc*4 + quad;
#pragma unroll
            for (int nt = 0; nt < 4; ++nt) {
                int row = wn*64 + nt*16 + lm;
                bfr[nt] = *(const s16x8*)&sB[row*64 + ((c8 ^ (row & 7)) * 8)];
            }
#pragma unroll
            for (int mt = 0; mt < 4; ++mt)
#pragma unroll
                for (int nt = 0; nt < 4; ++nt)
                    acc[mt][nt] = __builtin_amdgcn_mfma_f32_16x16x32_bf16(
                        af[mt], bfr[nt], acc[mt][nt], 0, 0, 0);
        }
        __syncthreads();
    }
#pragma unroll
    for (int mt = 0; mt < 4; ++mt)
#pragma unroll
        for (int nt = 0; nt < 4; ++nt)
#pragma unroll
            for (int i = 0; i < 4; ++i) {
                int row = bm*128 + wm*64 + mt*16 + quad*4 + i;
                int col = bn*128 + wn*64 + nt*16 + lm;
                E[(size_t)row*1024 + col] = f2bf(acc[mt][nt][i] + bias[nt]);
            }
}

// ---------------------------------------------------------------- Phase 2: recurrence
// 256 WGs = 16 row-groups x 16 col-groups. Each wave holds a [16 cols x 256 K]
// W_h slice in 128 VGPRs. K split across 4 waves -> LDS reduction.
// Cross-WG h exchange via sc0|sc1 (LLC-coherent) loads/stores + relaxed atomic
// counter. NO agent fences in the loop (they bulk-flush/invalidate L2).
__global__ __launch_bounds__(256, 1) void rnn_phase2(
    const float* __restrict__ h0,   // [256][1024] fp32
    const float* __restrict__ Wh,   // [1024][1024] fp32 (row = out col)
    const float* __restrict__ bh,   // [1024]
    const u16*   __restrict__ E,    // [512][256][1024] bf16
    u16*         __restrict__ hbuf, // [2][256][1024] bf16
    u32*         __restrict__ cnt,  // 16 counters spaced 32 u32 apart
    float*       __restrict__ hidden_out) // [256][1024] fp32
{
    __shared__ float red[4][16][68];
    int tid  = threadIdx.x;
    int lane = tid & 63, wv = tid >> 6;
    int lm   = lane & 15, quad = lane >> 4;
    int r    = blockIdx.x >> 4, c = blockIdx.x & 15;

    // --- persistent W_h fragments (one-time load, fp32 -> bf16)
    s16x8 wf[4][8];
#pragma unroll
    for (int ct = 0; ct < 4; ++ct)
#pragma unroll
        for (int kc = 0; kc < 8; ++kc) {
            int n = c*64 + ct*16 + lm;
            int k = wv*256 + kc*32 + quad*8;
            const float* p = Wh + (size_t)n*1024 + k;
            float4 x0 = ((const float4*)p)[0];
            float4 x1 = ((const float4*)p)[1];
            wf[ct][kc] = cvt8(x0, x1);
        }

    int m  = tid >> 4;          // reduce-phase row 0..15
    int n4 = (tid & 15) * 4;    // reduce-phase col base (of 64)
    float4 bh4 = *(const float4*)&bh[c*64 + n4];
    int rowA = r*16 + lm;
    u32* cptr = cnt + r*32;

    for (int t = 0; t < T_STEPS; ++t) {
        // E[t] is race-free (phase-1 data): normal cached load, issued early
        ushort4 e4 = *(const ushort4*)&E[(size_t)t*BH + (size_t)(r*16 + m)*1024 + c*64 + n4];

        if (t > 0) {
            if (tid == 0) {
                u32 target = (u32)(16*t);
                while (__hip_atomic_load(cptr, __ATOMIC_RELAXED, __HIP_MEMORY_SCOPE_AGENT) < target)
                    __builtin_amdgcn_s_sleep(1);
            }
            __syncthreads();   // release all waves; NO cache fence needed (loads bypass caches)
        }

        // A fragments: h rows for this group, this wave's K quarter
        s16x8 af[8];
        if (t == 0) {
#pragma unroll
            for (int kc = 0; kc < 8; ++kc) {
                const float* p = h0 + (size_t)rowA*1024 + wv*256 + kc*32 + quad*8;
                float4 x0 = ((const float4*)p)[0];
                float4 x1 = ((const float4*)p)[1];
                af[kc] = cvt8(x0, x1);
            }
        } else {
            const u16* hb = hbuf + (size_t)(t & 1)*BH;
#pragma unroll
            for (int kc = 0; kc < 8; ++kc)
                ldg_cv16_issue(&hb[(size_t)rowA*1024 + wv*256 + kc*32 + quad*8], &af[kc]);
            // single wait for the whole batch; "+v" ties af regs so no use precedes it
            asm volatile("s_waitcnt vmcnt(0)"
                         : "+v"(af[0]), "+v"(af[1]), "+v"(af[2]), "+v"(af[3]),
                           "+v"(af[4]), "+v"(af[5]), "+v"(af[6]), "+v"(af[7])
                         :: "memory");
        }

        f32x4 acc[4];
#pragma unroll
        for (int ct = 0; ct < 4; ++ct) acc[ct] = (f32x4){0.f, 0.f, 0.f, 0.f};
#pragma unroll
        for (int kc = 0; kc < 8; ++kc)
#pragma unroll
            for (int ct = 0; ct < 4; ++ct)
                acc[ct] = __builtin_amdgcn_mfma_f32_16x16x32_bf16(af[kc], wf[ct][kc], acc[ct], 0, 0, 0);

        // K-partial results -> LDS  (D layout: row = quad*4+i, col = lm)
#pragma unroll
        for (int ct = 0; ct < 4; ++ct)
#pragma unroll
            for (int i = 0; i < 4; ++i)
                red[wv][quad*4 + i][ct*16 + lm] = acc[ct][i];
        __syncthreads();

        // reduce 4 wave-partials + bias + e, sigmoid, store
        float4 p0 = *(const float4*)&red[0][m][n4];
        float4 p1 = *(const float4*)&red[1][m][n4];
        float4 p2 = *(const float4*)&red[2][m][n4];
        float4 p3 = *(const float4*)&red[3][m][n4];
        float4 s;
        s.x = p0.x + p1.x + p2.x + p3.x + bh4.x + bf2f(e4.x);
        s.y = p0.y + p1.y + p2.y + p3.y + bh4.y + bf2f(e4.y);
        s.z = p0.z + p1.z + p2.z + p3.z + bh4.z + bf2f(e4.z);
        s.w = p0.w + p1.w + p2.w + p3.w + bh4.w + bf2f(e4.w);
        float4 h;
        h.x = 1.f / (1.f + __expf(-s.x));
        h.y = 1.f / (1.f + __expf(-s.y));
        h.z = 1.f / (1.f + __expf(-s.z));
        h.w = 1.f / (1.f + __expf(-s.w));

        ushort4 hb4;
        hb4.x = f2bf(h.x); hb4.y = f2bf(h.y); hb4.z = f2bf(h.z); hb4.w = f2bf(h.w);
        // LLC-coherent store (write-through past L2)
        stg_cv8(&hbuf[(size_t)((t + 1) & 1)*BH + (size_t)(r*16 + m)*1024 + c*64 + n4], hb4);
        if (t == T_STEPS - 1)
            *(float4*)&hidden_out[(size_t)(r*16 + m)*1024 + c*64 + n4] = h;

        wait_vm0();          // own sc1 stores acked at the coherence point
        __syncthreads();     // all 256 threads' stores done + LDS reads done
        if (tid == 0)
            __hip_atomic_fetch_add(cptr, 1u, __ATOMIC_RELAXED, __HIP_MEMORY_SCOPE_AGENT);
    }
}

// ---------------------------------------------------------------- Phase 3: log_softmax(h W_o^T + b_o)
__global__ __launch_bounds__(64) void head_kernel(const float* __restrict__ h,
                                                  const float* __restrict__ Wo,
                                                  const float* __restrict__ bo,
                                                  float* __restrict__ out)
{
    int b = blockIdx.x, l = threadIdx.x;
    float a0 = 0.f, a1 = 0.f, a2 = 0.f, a3 = 0.f, a4 = 0.f;
    for (int k = l; k < DIM; k += 64) {
        float hv = h[b*DIM + k];
        a0 += hv * Wo[0*DIM + k];
        a1 += hv * Wo[1*DIM + k];
        a2 += hv * Wo[2*DIM + k];
        a3 += hv * Wo[3*DIM + k];
        a4 += hv * Wo[4*DIM + k];
    }
#pragma unroll
    for (int off = 32; off >= 1; off >>= 1) {
        a0 += __shfl_down(a0, off);
        a1 += __shfl_down(a1, off);
        a2 += __shfl_down(a2, off);
        a3 += __shfl_down(a3, off);
        a4 += __shfl_down(a4, off);
    }
    if (l == 0) {
        float v[5] = {a0 + bo[0], a1 + bo[1], a2 + bo[2], a3 + bo[3], a4 + bo[4]};
        float mx = v[0];
#pragma unroll
        for (int o = 1; o < 5; ++o) mx = fmaxf(mx, v[o]);
        float sum = 0.f;
#pragma unroll
        for (int o = 0; o < 5; ++o) sum += __expf(v[o] - mx);
        float lse = mx + __logf(sum);
#pragma unroll
        for (int o = 0; o < 5; ++o) out[b*NOUT + o] = v[o] - lse;
    }
}

// ---------------------------------------------------------------- launch
extern "C" void kernel_launch(void* const* d_in, const int* in_sizes, int n_in,
                              void* d_out, int out_size, void* d_ws, size_t ws_size,
                              hipStream_t stream)
{
    const float* X   = (const float*)d_in[0];
    const float* h0  = (const float*)d_in[1];
    const float* st  = (const float*)d_in[2];
    const float* Win = (const float*)d_in[3];
    const float* bin = (const float*)d_in[4];
    const float* Wh  = (const float*)d_in[5];
    const float* bhp = (const float*)d_in[6];
    const float* Wo  = (const float*)d_in[7];
    const float* bo  = (const float*)d_in[8];

    char* ws   = (char*)d_ws;
    u32*  cnt  = (u32*)ws;                                        // 4 KB
    u16*  hbuf = (u16*)(ws + 4096);                               // 1 MB
    u16*  Wbf  = (u16*)(ws + 4096 + (size_t)2*BH*2);              // 2 MB
    u16*  E    = (u16*)(ws + 4096 + (size_t)2*BH*2 + (size_t)DIM*DIM*2); // 268 MB

    float* out_lp = (float*)d_out;          // [256][5]
    float* out_h  = out_lp + BATCH*NOUT;    // [256][1024]
    float* out_st = out_h + BH;             // [256][1024]

    hipMemsetAsync(cnt, 0, 4096, stream);
    cvt_kernel<<<(DIM*DIM/4 + 255)/256, 256, 0, stream>>>(Win, Wbf, DIM*DIM/4);
    gemm_e<<<(T_STEPS*BATCH/128)*8, 256, 0, stream>>>(X, Wbf, bin, E);
    rnn_phase2<<<256, 256, 0, stream>>>(h0, Wh, bhp, E, hbuf, cnt, out_h);
    head_kernel<<<BATCH, 64, 0, stream>>>(out_h, Wo, bo, out_lp);
    hipMemcpyAsync(out_st, st, (size_t)BH*sizeof(float), hipMemcpyDeviceToDevice, stream);
}